// Round 2
// baseline (7439.104 us; speedup 1.0000x reference)
//
#include <hip/hip_runtime.h>
#include <hip/hip_bf16.h>

// ---------------------------------------------------------------------------
// EfficientVQBlock — round 1: dtype-adaptive correctness implementation.
// k_detect sniffs whether float tensors are stored fp32 or bf16 (flag in ws);
// all input loads and the output store branch on the flag.
// Decision path (qkv -> dw5 -> grouped pw -> VQ distances) uses fp64 accumulation
// with fp32 storage so argmin matches the numpy reference.
//
// Workspace layout (float offsets), peak ~151 MB:
//   qkv  @ 0          [0,        12582912)   live k_qkv..k_codes
//   dwb  @ 12582912   [12582912, 25165824)   live k_dw5..k_gpw
//   agg  @ 25165824   [25165824, 37748736)   live k_gpw..k_codes
//   qi   @ 12582912   (int, 262144)          overlays dead dwb, live k_codes..k_proj
//   sums @ 12845056   (2097152)              overlays dead dwb (memset AFTER k_gpw!)
//   cnt  @ 14942208   (int, 65536)           overlays dead dwb
//   x1   @ 33554432   [33554432, 37748736)   overlays dead agg tail, live k_proj..k_pw
//   h1   @ 0          [0,        16777216)   overlays dead qkv + qi/sums/cnt (dead)
//   h2   @ 16777216   [16777216, 33554432)   overlays dead dwb tail + agg head
//   flag @ 37748736   (int)                  live whole launch
// ---------------------------------------------------------------------------

typedef __hip_bfloat16 bf16;
#define DEV static __device__ __forceinline__

DEV float ldf(const void* p, size_t i, int f32) {
    return f32 ? ((const float*)p)[i]
               : __bfloat162float(((const bf16*)p)[i]);
}

#define BB   16
#define CIN  256
#define HH   32
#define WW   32
#define NN   1024
#define O1   768
#define MHG  16
#define DD   32
#define KK   256
#define EE   1024

// ---- K0: detect input storage dtype (fp32 vs bf16) --------------------------
__global__ void k_detect(const void* x, int* flag) {
    __shared__ int s[256];
    int t = threadIdx.x;
    const unsigned short* u = (const unsigned short*)x;
    int weird = 0;
    for (int i = t; i < 4096; i += 256) {
        int e = (u[i] >> 7) & 0xFF;       // bf16 exponent field
        if (e >= 0xA0) weird++;           // |v| >= ~8e9 or NaN/Inf: impossible for N(0,1) bf16
    }
    s[t] = weird;
    __syncthreads();
    for (int o = 128; o > 0; o >>= 1) {
        if (t < o) s[t] += s[t + o];
        __syncthreads();
    }
    if (t == 0) flag[0] = (s[0] >= 4) ? 1 : 0;  // 1 = fp32 storage, 0 = bf16
}

// ---- K1: qkv = x (256ch) -> 768ch per-pixel matmul --------------------------
__global__ void k_qkv(const void* __restrict__ x, const void* __restrict__ w,
                      const int* __restrict__ fl, float* __restrict__ qkv) {
    int f32 = *fl;
    int idx = blockIdx.x * 256 + threadIdx.x;       // B*768*1024
    int p  = idx & (NN - 1);
    int bo = idx >> 10;                              // b*768 + o
    int b  = bo / O1;
    int o  = bo - b * O1;
    size_t xb = (size_t)b * CIN * NN + p;
    size_t wo = (size_t)o * CIN;
    double acc = 0.0;
#pragma unroll 8
    for (int c = 0; c < CIN; ++c)
        acc += (double)ldf(x, xb + (size_t)c * NN, f32) * (double)ldf(w, wo + c, f32);
    qkv[idx] = (float)acc;
}

// ---- K2: depthwise 5x5, pad 2 ----------------------------------------------
__global__ void k_dw5(const float* __restrict__ qkv, const void* __restrict__ w,
                      const int* __restrict__ fl, float* __restrict__ outp) {
    int f32 = *fl;
    int idx = blockIdx.x * 256 + threadIdx.x;       // B*768*1024
    int p  = idx & (NN - 1);
    int y  = p >> 5, xx = p & 31;
    int bo = idx >> 10;
    int b  = bo / O1;
    int o  = bo - b * O1;
    const float* base = qkv + (size_t)bo * NN;
    size_t wr = (size_t)o * 25;
    double acc = 0.0;
    for (int dy = 0; dy < 5; ++dy) {
        int yy = y + dy - 2;
        if (yy < 0 || yy >= HH) continue;
        for (int dx = 0; dx < 5; ++dx) {
            int xc = xx + dx - 2;
            if (xc < 0 || xc >= WW) continue;
            acc += (double)base[yy * WW + xc] * (double)ldf(w, wr + dy * 5 + dx, f32);
        }
    }
    outp[idx] = (float)acc;
}

// ---- K3: grouped 1x1 (24 groups of 32->32) ---------------------------------
__global__ void k_gpw(const float* __restrict__ dw, const void* __restrict__ w,
                      const int* __restrict__ fl, float* __restrict__ agg) {
    int f32 = *fl;
    int idx = blockIdx.x * 256 + threadIdx.x;       // B*768*1024
    int p  = idx & (NN - 1);
    int bo = idx >> 10;
    int b  = bo / O1;
    int o  = bo - b * O1;
    int g  = o >> 5;
    const float* base = dw + ((size_t)(b * O1 + g * DD)) * NN + p;
    size_t wr = (size_t)o * DD;
    double acc = 0.0;
#pragma unroll
    for (int i = 0; i < DD; ++i)
        acc += (double)base[(size_t)i * NN] * (double)ldf(w, wr + i, f32);
    agg[idx] = (float)acc;
}

// ---- K4: VQ codes for q,k + scatter v into sums/counts ----------------------
__global__ void k_codes(const float* __restrict__ qkv, const float* __restrict__ agg,
                        const void* __restrict__ cb, const int* __restrict__ fl,
                        int* __restrict__ qi,
                        float* __restrict__ sums, int* __restrict__ counts) {
    __shared__ float  s_cb[KK * DD];
    __shared__ double s_cc[KK];
    int f32 = *fl;
    int t = threadIdx.x;                             // 256
    for (int i = t; i < KK * DD; i += 256) s_cb[i] = ldf(cb, i, f32);
    __syncthreads();
    {
        double c2 = 0.0;
        const float* cr = s_cb + t * DD;
#pragma unroll
        for (int d = 0; d < DD; ++d) c2 += (double)cr[d] * (double)cr[d];
        s_cc[t] = c2;
    }
    __syncthreads();

    int idx = blockIdx.x * 256 + t;                  // B*16*1024
    int n  = idx & (NN - 1);
    int bm = idx >> 10;                              // b*16 + mg
    int mg = bm & 15;
    int b  = bm >> 4;
    int cm = mg * 96;
    const float* sp = (cm < O1)
        ? (qkv + ((size_t)(b * O1 + cm)) * NN + n)
        : (agg + ((size_t)(b * O1 + cm - O1)) * NN + n);
    float q[DD], k[DD], v[DD];
    double qq = 0.0, k2 = 0.0;
#pragma unroll
    for (int d = 0; d < DD; ++d) {
        q[d] = sp[(size_t)d * NN];
        k[d] = sp[(size_t)(DD + d) * NN];
        v[d] = sp[(size_t)(2 * DD + d) * NN];
        qq += (double)q[d] * (double)q[d];
        k2 += (double)k[d] * (double)k[d];
    }
    double bestq = 1e300, bestk = 1e300;
    int biq = 0, bik = 0;
    for (int c = 0; c < KK; ++c) {
        const float* cr = s_cb + c * DD;
        double dotq = 0.0, dotk = 0.0;
#pragma unroll
        for (int d = 0; d < DD; ++d) {
            double cd = (double)cr[d];
            dotq += (double)q[d] * cd;
            dotk += (double)k[d] * cd;
        }
        double dq = qq - 2.0 * dotq + s_cc[c];
        double dk = k2 - 2.0 * dotk + s_cc[c];
        if (dq < bestq) { bestq = dq; biq = c; }
        if (dk < bestk) { bestk = dk; bik = c; }
    }
    qi[idx] = biq;
    float* s = sums + ((size_t)bm * KK + bik) * DD;
#pragma unroll
    for (int d = 0; d < DD; ++d) atomicAdd(&s[d], v[d]);
    atomicAdd(&counts[bm * KK + bik], 1);
}

// ---- K5: bucket = sums / max(counts,1) (in place) ---------------------------
__global__ void k_bucket(float* __restrict__ sums, const int* __restrict__ counts) {
    int idx = blockIdx.x * 256 + threadIdx.x;        // B*16*256*32
    float c = (float)counts[idx >> 5];
    sums[idx] = sums[idx] / fmaxf(c, 1.0f);
}

// ---- K6: gather bucket by qi, proj 512->256, bn1, residual -> x1 ------------
__global__ void k_proj(const void* __restrict__ x, const float* __restrict__ bucket,
                       const int* __restrict__ qi, const void* __restrict__ wp,
                       const void* __restrict__ g, const void* __restrict__ be,
                       const void* __restrict__ mm, const void* __restrict__ vv,
                       const int* __restrict__ fl, float* __restrict__ x1) {
    int f32 = *fl;
    int idx = blockIdx.x * 256 + threadIdx.x;        // B*256*1024
    int p  = idx & (NN - 1);
    int bo = idx >> 10;
    int b  = bo >> 8;
    int o  = bo & 255;
    const int* qrow = qi + (size_t)(b * MHG) * NN + p;
    size_t wrow = (size_t)o * (MHG * DD);
    const float* bb = bucket + (size_t)b * MHG * KK * DD;
    double acc = 0.0;
    for (int mg = 0; mg < MHG; ++mg) {
        int code = qrow[(size_t)mg * NN];
        const float* bk = bb + ((size_t)mg * KK + code) * DD;
#pragma unroll
        for (int d = 0; d < DD; ++d)
            acc += (double)bk[d] * (double)ldf(wp, wrow + mg * DD + d, f32);
    }
    float scale = ldf(g, o, f32) / sqrtf(ldf(vv, o, f32) + 1e-5f);
    float pr = ((float)acc - ldf(mm, o, f32)) * scale + ldf(be, o, f32);
    x1[idx] = ldf(x, idx, f32) + pr;
}

// ---- K7: expand 256->1024 + hswish -----------------------------------------
__global__ void k_exp(const float* __restrict__ x1, const void* __restrict__ w,
                      const void* __restrict__ bias, const int* __restrict__ fl,
                      float* __restrict__ h1) {
    int f32 = *fl;
    int idx = blockIdx.x * 256 + threadIdx.x;        // B*1024*1024
    int p  = idx & (NN - 1);
    int be_ = idx >> 10;
    int b  = be_ >> 10;
    int e  = be_ & (EE - 1);
    const float* xb = x1 + (size_t)b * CIN * NN + p;
    size_t wr = (size_t)e * CIN;
    float acc = ldf(bias, e, f32);
#pragma unroll 8
    for (int c = 0; c < CIN; ++c)
        acc = fmaf(ldf(w, wr + c, f32), xb[(size_t)c * NN], acc);
    float t = fminf(fmaxf(acc + 3.0f, 0.0f), 6.0f);
    h1[idx] = (acc * t) / 6.0f;
}

// ---- K8: depthwise 3x3 + bias + hswish --------------------------------------
__global__ void k_dw3(const float* __restrict__ h1, const void* __restrict__ w,
                      const void* __restrict__ bias, const int* __restrict__ fl,
                      float* __restrict__ h2) {
    int f32 = *fl;
    int idx = blockIdx.x * 256 + threadIdx.x;        // B*1024*1024
    int p  = idx & (NN - 1);
    int y  = p >> 5, xx = p & 31;
    int be_ = idx >> 10;                             // b*1024 + e
    int e  = be_ & (EE - 1);
    const float* base = h1 + (size_t)be_ * NN;
    size_t wr = (size_t)e * 9;
    float acc = ldf(bias, e, f32);
    for (int dy = 0; dy < 3; ++dy) {
        int yy = y + dy - 1;
        if (yy < 0 || yy >= HH) continue;
        for (int dx = 0; dx < 3; ++dx) {
            int xc = xx + dx - 1;
            if (xc < 0 || xc >= WW) continue;
            acc = fmaf(ldf(w, wr + dy * 3 + dx, f32), base[yy * WW + xc], acc);
        }
    }
    float t = fminf(fmaxf(acc + 3.0f, 0.0f), 6.0f);
    h2[idx] = (acc * t) / 6.0f;
}

// ---- K9: pw 1024->256, bn2, + x1 -> out -------------------------------------
__global__ void k_pw(const float* __restrict__ h2, const void* __restrict__ w,
                     const float* __restrict__ x1,
                     const void* __restrict__ g, const void* __restrict__ be,
                     const void* __restrict__ mm, const void* __restrict__ vv,
                     const int* __restrict__ fl, void* __restrict__ out) {
    int f32 = *fl;
    int idx = blockIdx.x * 256 + threadIdx.x;        // B*256*1024
    int p  = idx & (NN - 1);
    int bo = idx >> 10;
    int b  = bo >> 8;
    int o  = bo & 255;
    const float* hb = h2 + (size_t)b * EE * NN + p;
    size_t wr = (size_t)o * EE;
    float acc = 0.0f;
#pragma unroll 8
    for (int e = 0; e < EE; ++e)
        acc = fmaf(ldf(w, wr + e, f32), hb[(size_t)e * NN], acc);
    float scale = ldf(g, o, f32) / sqrtf(ldf(vv, o, f32) + 1e-5f);
    float val = (acc - ldf(mm, o, f32)) * scale + ldf(be, o, f32) + x1[idx];
    if (f32) ((float*)out)[idx] = val;
    else     ((bf16*)out)[idx] = __float2bfloat16(val);
}

// ---------------------------------------------------------------------------
extern "C" void kernel_launch(void* const* d_in, const int* in_sizes, int n_in,
                              void* d_out, int out_size, void* d_ws, size_t ws_size,
                              hipStream_t stream) {
    const void* x      = d_in[0];
    const void* w_qkv  = d_in[1];
    const void* w_dw5  = d_in[2];
    const void* w_pw_g = d_in[3];
    const void* cb     = d_in[4];
    const void* w_proj = d_in[5];
    const void* bn1g   = d_in[6];
    const void* bn1b   = d_in[7];
    const void* bn1m   = d_in[8];
    const void* bn1v   = d_in[9];
    const void* w_exp  = d_in[10];
    const void* b_exp  = d_in[11];
    const void* w_dw3  = d_in[12];
    const void* b_dw3  = d_in[13];
    const void* w_pw   = d_in[14];
    const void* bn2g   = d_in[15];
    const void* bn2b   = d_in[16];
    const void* bn2m   = d_in[17];
    const void* bn2v   = d_in[18];

    float* ws   = (float*)d_ws;
    float* qkv  = ws;                       // [0, 12582912)
    float* dwb  = ws + 12582912;            // [12582912, 25165824)
    float* agg  = ws + 25165824;            // [25165824, 37748736)
    int*   qi   = (int*)(ws + 12582912);    // overlays dead dwb
    float* sums = ws + 12845056;            // overlays dead dwb
    int*   cnt  = (int*)(ws + 14942208);    // overlays dead dwb
    float* x1   = ws + 33554432;            // overlays dead agg tail
    float* h1   = ws;                       // overlays dead qkv/qi/sums
    float* h2   = ws + 16777216;            // overlays dead dwb tail + agg head
    int*   flag = (int*)(ws + 37748736);    // live whole launch

    k_detect<<<1,     256, 0, stream>>>(x, flag);
    k_qkv   <<<49152, 256, 0, stream>>>(x, w_qkv, flag, qkv);
    k_dw5   <<<49152, 256, 0, stream>>>(qkv, w_dw5, flag, dwb);
    k_gpw   <<<49152, 256, 0, stream>>>(dwb, w_pw_g, flag, agg);
    // sums/cnt overlay dwb: memset only after k_gpw has consumed dwb
    hipMemsetAsync(sums, 0, (size_t)(2097152 + 65536) * sizeof(float), stream);
    k_codes <<<1024,  256, 0, stream>>>(qkv, agg, cb, flag, qi, sums, cnt);
    k_bucket<<<8192,  256, 0, stream>>>(sums, cnt);
    k_proj  <<<16384, 256, 0, stream>>>(x, sums, qi, w_proj, bn1g, bn1b, bn1m, bn1v, flag, x1);
    k_exp   <<<65536, 256, 0, stream>>>(x1, w_exp, b_exp, flag, h1);
    k_dw3   <<<65536, 256, 0, stream>>>(h1, w_dw3, b_dw3, flag, h2);
    k_pw    <<<16384, 256, 0, stream>>>(h2, w_pw, x1, bn2g, bn2b, bn2m, bn2v, flag, (void*)d_out);
}